// Round 5
// baseline (3131.112 us; speedup 1.0000x reference)
//
#include <hip/hip_runtime.h>
#include <hip/hip_bf16.h>

typedef __hip_bfloat16 bf16;
typedef __bf16 bfv8 __attribute__((ext_vector_type(8)));
typedef float fv4 __attribute__((ext_vector_type(4)));

#define B_  8
#define T_  1024
#define INP 512
#define D_  1024
#define I_  2048
#define N_  64
#define H_  16
#define P_  128
#define L_  4
#define OUT_ 512
#define CB_ 1024
#define CONV_DIM 2176
#define PROJ 4240
#define M_  (B_*T_)       // 8192 rows
#define TC  64            // scan chunk length
#define NC  (T_/TC)       // 16 chunks

typedef const __attribute__((address_space(1))) void gv_t;
typedef __attribute__((address_space(3))) void lv_t;

__device__ __forceinline__ void load_lds16(const bf16* g, bf16* l) {
    __builtin_amdgcn_global_load_lds((gv_t*)g, (lv_t*)l, 16, 0, 0);
}

// ---------------------------------------------------------------------------
// fp32 -> bf16 copy
// ---------------------------------------------------------------------------
__global__ __launch_bounds__(256) void ingest_k(const float* __restrict__ src,
                                                bf16* __restrict__ dst, int n) {
    int i = blockIdx.x * 256 + threadIdx.x;
    if (i >= n) return;
    dst[i] = __float2bfloat16(src[i]);
}

// ---------------------------------------------------------------------------
// Transpose fp32 [R][C] -> bf16 [Cp][R], zero-padding rows C..Cp.
// ---------------------------------------------------------------------------
__global__ __launch_bounds__(256) void transpose_any(const float* __restrict__ in,
                                                     size_t off,
                                                     bf16* __restrict__ out,
                                                     int R, int C) {
    __shared__ bf16 tile[32][33];
    int c0 = blockIdx.x * 32, r0 = blockIdx.y * 32;
    int tx = threadIdx.x, ty = threadIdx.y;
#pragma unroll
    for (int i = 0; i < 4; ++i) {
        int r = r0 + ty + i * 8, c = c0 + tx;
        bf16 v = __float2bfloat16(0.f);
        if (c < C) v = __float2bfloat16(in[off + (size_t)r * C + c]);
        tile[ty + i * 8][tx] = v;
    }
    __syncthreads();
#pragma unroll
    for (int i = 0; i < 4; ++i) {
        int c = c0 + ty + i * 8;
        out[(size_t)c * R + r0 + tx] = tile[tx][ty + i * 8];
    }
}

// ---------------------------------------------------------------------------
// GEMM: C[M,N] = A[M,K] @ Bt[N,K]^T. 128x128 tile, BK=32, 4 waves, 4x4 mfma.
// Staging via global_load_lds width=16 (m97 pattern): LDS rows are unpadded
// 32-bf16 (64 B), wave-uniform LDS base + lane*16 B covers 16 rows/issue.
// MODE 0: outF = acc + bias (fp32)    MODE 1: split gate/hBC/dt
// MODE 2: outF += acc (fp32)
// ---------------------------------------------------------------------------
template <int MODE>
__global__ __launch_bounds__(256) void gemm_bt(const bf16* __restrict__ A,
                                               const bf16* __restrict__ Bt,
                                               int K, int N,
                                               const bf16* __restrict__ bias,
                                               float* __restrict__ outF,
                                               bf16* __restrict__ outB,
                                               bf16* __restrict__ outB2,
                                               float* __restrict__ outF2) {
    __shared__ bf16 As[128 * 32];
    __shared__ bf16 Bs[128 * 32];
    const int tid = threadIdx.x;
    const int m0 = blockIdx.y * 128;
    const int n0 = blockIdx.x * 128;
    const int lane = tid & 63, wv = tid >> 6;
    const int wm = (wv >> 1) * 64, wn = (wv & 1) * 64;
    const int l16 = lane & 15, quad = lane >> 4;
    const int sr = lane >> 2, sc = (lane & 3) * 8;   // staging row/col within 16-row slab

    fv4 acc[4][4] = {};

    for (int k0 = 0; k0 < K; k0 += 32) {
        __syncthreads();
        {
            const bf16* gA0 = &A [(size_t)(m0 + wv * 16      + sr) * K + k0 + sc];
            const bf16* gA1 = &A [(size_t)(m0 + wv * 16 + 64 + sr) * K + k0 + sc];
            const bf16* gB0 = &Bt[(size_t)(n0 + wv * 16      + sr) * K + k0 + sc];
            const bf16* gB1 = &Bt[(size_t)(n0 + wv * 16 + 64 + sr) * K + k0 + sc];
            load_lds16(gA0, &As[(wv * 16) * 32]);
            load_lds16(gA1, &As[(wv * 16 + 64) * 32]);
            load_lds16(gB0, &Bs[(wv * 16) * 32]);
            load_lds16(gB1, &Bs[(wv * 16 + 64) * 32]);
        }
        __syncthreads();
        bfv8 afr[4], bfr[4];
#pragma unroll
        for (int i = 0; i < 4; ++i)
            afr[i] = *(const bfv8*)&As[(wm + i * 16 + l16) * 32 + quad * 8];
#pragma unroll
        for (int i = 0; i < 4; ++i)
            bfr[i] = *(const bfv8*)&Bs[(wn + i * 16 + l16) * 32 + quad * 8];
#pragma unroll
        for (int mt = 0; mt < 4; ++mt)
#pragma unroll
            for (int nt = 0; nt < 4; ++nt)
                acc[mt][nt] = __builtin_amdgcn_mfma_f32_16x16x32_bf16(
                    afr[mt], bfr[nt], acc[mt][nt], 0, 0, 0);
    }

#pragma unroll
    for (int mt = 0; mt < 4; ++mt) {
#pragma unroll
        for (int nt = 0; nt < 4; ++nt) {
#pragma unroll
            for (int i = 0; i < 4; ++i) {
                int row = m0 + wm + mt * 16 + quad * 4 + i;
                int col = n0 + wn + nt * 16 + l16;
                float v = acc[mt][nt][i];
                if (MODE == 0) {
                    v += __bfloat162float(bias[col]);
                    outF[(size_t)row * N + col] = v;
                } else if (MODE == 1) {
                    if (col < I_)
                        outB[(size_t)row * I_ + col] = __float2bfloat16(v);
                    else if (col < I_ + CONV_DIM)
                        outB2[(size_t)row * CONV_DIM + (col - I_)] = __float2bfloat16(v);
                    else if (col < PROJ)
                        outF2[(size_t)row * H_ + (col - (I_ + CONV_DIM))] = v;
                } else if (MODE == 2) {
                    outF[(size_t)row * N + col] += v;
                }
            }
        }
    }
}

// ---------------------------------------------------------------------------
__global__ __launch_bounds__(256) void rmsnorm_k(const float* __restrict__ x,
                                                 const bf16* __restrict__ w,
                                                 bf16* __restrict__ out) {
    int row = blockIdx.x, tid = threadIdx.x;
    float4 v = *(const float4*)&x[(size_t)row * D_ + tid * 4];
    float ss = v.x * v.x + v.y * v.y + v.z * v.z + v.w * v.w;
#pragma unroll
    for (int off = 32; off; off >>= 1) ss += __shfl_down(ss, off);
    __shared__ float sb[4];
    if ((tid & 63) == 0) sb[tid >> 6] = ss;
    __syncthreads();
    ss = sb[0] + sb[1] + sb[2] + sb[3];
    float rs = rsqrtf(ss * (1.f / D_) + 1e-6f);
    float xv[4] = {v.x, v.y, v.z, v.w};
#pragma unroll
    for (int j = 0; j < 4; ++j)
        out[(size_t)row * D_ + tid * 4 + j] =
            __float2bfloat16(xv[j] * rs * __bfloat162float(w[tid * 4 + j]));
}

// ---------------------------------------------------------------------------
__global__ __launch_bounds__(256) void gatednorm_k(const bf16* __restrict__ y,
                                                   const bf16* __restrict__ g,
                                                   const bf16* __restrict__ w,
                                                   bf16* __restrict__ out) {
    int row = blockIdx.x, tid = threadIdx.x;
    size_t base = (size_t)row * I_ + tid * 8;
    bf16 yv[8], gv[8];
    *(uint4*)yv = *(const uint4*)&y[base];
    *(uint4*)gv = *(const uint4*)&g[base];
    float vv[8]; float ss = 0.f;
#pragma unroll
    for (int j = 0; j < 8; ++j) {
        float yf = __bfloat162float(yv[j]);
        float gf = __bfloat162float(gv[j]);
        float sig = 1.f / (1.f + expf(-gf));
        vv[j] = yf * gf * sig;
        ss += vv[j] * vv[j];
    }
#pragma unroll
    for (int off = 32; off; off >>= 1) ss += __shfl_down(ss, off);
    __shared__ float sb[4];
    if ((tid & 63) == 0) sb[tid >> 6] = ss;
    __syncthreads();
    ss = sb[0] + sb[1] + sb[2] + sb[3];
    float rs = rsqrtf(ss * (1.f / I_) + 1e-6f);
    bf16 ov[8];
#pragma unroll
    for (int j = 0; j < 8; ++j)
        ov[j] = __float2bfloat16(vv[j] * rs * __bfloat162float(w[tid * 8 + j]));
    *(uint4*)&out[base] = *(uint4*)ov;
}

// ---------------------------------------------------------------------------
__global__ __launch_bounds__(256) void conv_k(const bf16* __restrict__ hbc,
                                              const bf16* __restrict__ w,
                                              const bf16* __restrict__ bias,
                                              bf16* __restrict__ xs,
                                              float* __restrict__ bc) {
    int cq = blockIdx.x * 256 + threadIdx.x;
    if (cq >= CONV_DIM / 4) return;
    int c = cq * 4;
    int bt = blockIdx.y;
    int t = bt & (T_ - 1);
    float acc[4];
#pragma unroll
    for (int j = 0; j < 4; ++j) acc[j] = __bfloat162float(bias[c + j]);
#pragma unroll
    for (int k = 0; k < 3; ++k) {
        int tt = t - 2 + k;
        if (tt < 0) continue;
        const bf16* src = &hbc[(size_t)(bt - 2 + k) * CONV_DIM + c];
#pragma unroll
        for (int j = 0; j < 4; ++j)
            acc[j] = fmaf(__bfloat162float(w[k * CONV_DIM + c + j]),
                          __bfloat162float(src[j]), acc[j]);
    }
#pragma unroll
    for (int j = 0; j < 4; ++j) {
        float v = acc[j];
        v = v / (1.f + expf(-v));     // silu
        if (c + j < I_) xs[(size_t)bt * I_ + c + j] = __float2bfloat16(v);
        else            bc[(size_t)bt * 128 + (c + j - I_)] = v;
    }
}

// ---------------------------------------------------------------------------
// dt prep: per (b,h,chunk) sequential over the chunk.
//   dt = softplus(dtraw + bias); dA = exp(dt*a); gamma = cumprod(dA);
//   wco = dt/gamma (normalized-scan input coefficient), gma = gamma.
// One lane per (b,ci,h), h fastest for coalescing. fp32 params read directly.
// ---------------------------------------------------------------------------
__global__ __launch_bounds__(256) void dtprep_k(const float* __restrict__ dtraw,
                                                const float* __restrict__ dtb,
                                                const float* __restrict__ alog,
                                                float* __restrict__ wco,
                                                float* __restrict__ gma) {
    int idx = blockIdx.x * 256 + threadIdx.x;       // b*256 + ci*16 + h
    if (idx >= B_ * NC * H_) return;
    int h = idx & 15, ci = (idx >> 4) & (NC - 1), b = idx >> 8;
    float a = -expf(alog[h]);
    float bz = dtb[h];
    float g = 1.f;
    int base = (b * T_ + ci * TC) * H_ + h;
    for (int s = 0; s < TC; ++s) {
        float z = dtraw[base + s * H_] + bz;
        float dt = fmaxf(z, 0.f) + log1pf(expf(-fabsf(z)));
        g *= expf(dt * a);
        wco[base + s * H_] = dt / g;
        gma[base + s * H_] = g;
    }
}

// ---------------------------------------------------------------------------
// Scan pass A (normalized form): per (b,h,chunk) local scan from zero state.
//   S~_t = S~_{t-1} + (dt_t/gamma_t) * x * B_t         (wco precomputed)
//   y_t  = gamma_t * (C_t . S~_t) + D*x
// stores S_fin(real) = gamma_last * S~_last.
// B/C loads are block-uniform float4 -> scalar loads; no readlane needed.
// ---------------------------------------------------------------------------
__global__ __launch_bounds__(128) void scan_local_k(const bf16* __restrict__ xs,
                                                    const float* __restrict__ bc,
                                                    const float* __restrict__ wco,
                                                    const float* __restrict__ gma,
                                                    const float* __restrict__ dvec,
                                                    bf16* __restrict__ yout,
                                                    bf16* __restrict__ sfin) {
    int bid = blockIdx.x;                   // b*256 + h*16 + ci
    int ci = bid & (NC - 1);
    int h  = (bid >> 4) & (H_ - 1);
    int b  = bid >> 8;
    int p = threadIdx.x;
    float Dv = dvec[h];
    float st[64];
#pragma unroll
    for (int n = 0; n < 64; ++n) st[n] = 0.f;
    int bt0 = b * T_ + ci * TC;
    const bf16* xptr = xs + (size_t)bt0 * I_ + h * P_ + p;
    bf16* yptr = yout + (size_t)bt0 * I_ + h * P_ + p;
    float xv_n = __bfloat162float(xptr[0]);
    for (int s = 0; s < TC; ++s) {
        float xv = xv_n;
        if (s + 1 < TC) xv_n = __bfloat162float(xptr[(size_t)(s + 1) * I_]);
        float w = wco[(bt0 + s) * H_ + h];          // uniform -> s_load
        float g = gma[(bt0 + s) * H_ + h];
        float cc = w * xv;
        const float4* B4 = (const float4*)&bc[(size_t)(bt0 + s) * 128];
#pragma unroll
        for (int j = 0; j < 16; ++j) {
            float4 bv = B4[j];                      // uniform
            st[4 * j + 0] = fmaf(cc, bv.x, st[4 * j + 0]);
            st[4 * j + 1] = fmaf(cc, bv.y, st[4 * j + 1]);
            st[4 * j + 2] = fmaf(cc, bv.z, st[4 * j + 2]);
            st[4 * j + 3] = fmaf(cc, bv.w, st[4 * j + 3]);
        }
        float y0 = 0.f, y1 = 0.f, y2 = 0.f, y3 = 0.f;
#pragma unroll
        for (int j = 0; j < 16; ++j) {
            float4 cv = B4[16 + j];                 // C block, uniform
            y0 = fmaf(st[4 * j + 0], cv.x, y0);
            y1 = fmaf(st[4 * j + 1], cv.y, y1);
            y2 = fmaf(st[4 * j + 2], cv.z, y2);
            y3 = fmaf(st[4 * j + 3], cv.w, y3);
        }
        yptr[(size_t)s * I_] = __float2bfloat16(fmaf(g, (y0 + y1) + (y2 + y3), Dv * xv));
    }
    float G = gma[(bt0 + TC - 1) * H_ + h];
    bf16* sf = sfin + (size_t)bid * (128 * 64);
#pragma unroll
    for (int n = 0; n < 64; ++n) sf[n * 128 + p] = __float2bfloat16(st[n] * G);
}

// ---------------------------------------------------------------------------
// Pass B: sequential chunk combine; sbuf[c] becomes S_init of chunk c.
// ---------------------------------------------------------------------------
__global__ __launch_bounds__(128) void scan_combine_k(bf16* __restrict__ sbuf,
                                                      const float* __restrict__ gma) {
    int bh = blockIdx.x;                    // b*16 + h
    int b = bh >> 4, h = bh & (H_ - 1);
    int p = threadIdx.x;
    float S[64];
#pragma unroll
    for (int n = 0; n < 64; ++n) S[n] = 0.f;
    for (int ci = 0; ci < NC; ++ci) {
        bf16* base = sbuf + ((size_t)bh * NC + ci) * (128 * 64);
        float G = gma[(b * T_ + ci * TC + TC - 1) * H_ + h];
#pragma unroll
        for (int n = 0; n < 64; ++n) {
            float tmp = __bfloat162float(base[n * 128 + p]);  // S_fin of chunk ci
            base[n * 128 + p] = __float2bfloat16(S[n]);       // S_init of chunk ci
            S[n] = fmaf(G, S[n], tmp);
        }
    }
}

// ---------------------------------------------------------------------------
// Pass C: y += gamma_t * (C_t . S_init)
// ---------------------------------------------------------------------------
__global__ __launch_bounds__(128) void scan_correct_k(const bf16* __restrict__ sinit,
                                                      const float* __restrict__ gma,
                                                      const float* __restrict__ bc,
                                                      bf16* __restrict__ yout) {
    int bid = blockIdx.x;
    int ci = bid & (NC - 1);
    if (ci == 0) return;
    int h = (bid >> 4) & (H_ - 1);
    int b = bid >> 8;
    int p = threadIdx.x;
    const bf16* sb = sinit + (size_t)bid * (128 * 64);
    float S[64];
#pragma unroll
    for (int n = 0; n < 64; ++n) S[n] = __bfloat162float(sb[n * 128 + p]);
    int bt0 = b * T_ + ci * TC;
    bf16* yptr = yout + (size_t)bt0 * I_ + h * P_ + p;
    for (int s = 0; s < TC; ++s) {
        float g = gma[(bt0 + s) * H_ + h];          // uniform
        const float4* C4 = (const float4*)&bc[(size_t)(bt0 + s) * 128 + 64];
        float y0 = 0.f, y1 = 0.f, y2 = 0.f, y3 = 0.f;
#pragma unroll
        for (int j = 0; j < 16; ++j) {
            float4 cv = C4[j];
            y0 = fmaf(S[4 * j + 0], cv.x, y0);
            y1 = fmaf(S[4 * j + 1], cv.y, y1);
            y2 = fmaf(S[4 * j + 2], cv.z, y2);
            y3 = fmaf(S[4 * j + 3], cv.w, y3);
        }
        float y = __bfloat162float(yptr[(size_t)s * I_]);
        yptr[(size_t)s * I_] = __float2bfloat16(fmaf(g, (y0 + y1) + (y2 + y3), y));
    }
}

// ---------------------------------------------------------------------------
__global__ __launch_bounds__(256) void cast_f2b_k(const float* __restrict__ in,
                                                  bf16* __restrict__ out) {
    int i = (blockIdx.x * 256 + threadIdx.x) * 4;
    float4 v = *(const float4*)&in[i];
    bf16 ov[4] = {__float2bfloat16(v.x), __float2bfloat16(v.y),
                  __float2bfloat16(v.z), __float2bfloat16(v.w)};
    *(uint2*)&out[i] = *(uint2*)ov;
}

// ---------------------------------------------------------------------------

static inline size_t align256(size_t x) { return (x + 255) & ~(size_t)255; }

extern "C" void kernel_launch(void* const* d_in, const int* in_sizes, int n_in,
                              void* d_out, int out_size, void* d_ws, size_t ws_size,
                              hipStream_t stream) {
    const float* x_in     = (const float*)d_in[0];
    const float* in_w     = (const float*)d_in[1];
    const float* in_b     = (const float*)d_in[2];
    const float* norm_w   = (const float*)d_in[3];
    const float* mix_in_w = (const float*)d_in[4];
    const float* conv_w   = (const float*)d_in[5];
    const float* conv_b   = (const float*)d_in[6];
    const float* dt_bias  = (const float*)d_in[7];
    const float* A_log    = (const float*)d_in[8];
    const float* Dvec     = (const float*)d_in[9];
    const float* gnorm_w  = (const float*)d_in[10];
    const float* mix_out_w= (const float*)d_in[11];
    const float* out_w    = (const float*)d_in[12];
    const float* out_b    = (const float*)d_in[13];
    const float* code_w   = (const float*)d_in[14];
    const float* code_b   = (const float*)d_in[15];
    float* outF0 = (float*)d_out;                       // [8192][512]
    float* outF1 = (float*)d_out + (size_t)M_ * OUT_;   // [8192][1024]

    char* p = (char*)d_ws;
    auto alloc = [&](size_t bytes) -> char* { char* r = p; p += align256(bytes); return r; };

    bf16*  xb       = (bf16*)alloc((size_t)M_ * INP * 2);
    bf16*  v_inb    = (bf16*)alloc(D_ * 2);
    bf16*  v_normw  = (bf16*)alloc(L_ * D_ * 2);
    bf16*  v_convw  = (bf16*)alloc(L_ * 3 * CONV_DIM * 2);
    bf16*  v_convb  = (bf16*)alloc(L_ * CONV_DIM * 2);
    bf16*  v_gnw    = (bf16*)alloc(L_ * I_ * 2);
    bf16*  v_outb   = (bf16*)alloc(OUT_ * 2);
    bf16*  v_codeb  = (bf16*)alloc(CB_ * 2);
    bf16*  wt_in    = (bf16*)alloc((size_t)1024 * 512 * 2);
    bf16*  wt_big   = (bf16*)alloc((size_t)4352 * 1024 * 2);   // per-layer reuse
    bf16*  wt_small = (bf16*)alloc((size_t)1024 * 2048 * 2);   // per-layer reuse
    bf16*  wt_out   = (bf16*)alloc((size_t)512 * 1024 * 2);
    bf16*  wt_code  = (bf16*)alloc((size_t)1024 * 1024 * 2);
    float* hbuf     = (float*)alloc((size_t)M_ * D_ * 4);      // residual fp32
    bf16*  hn       = (bf16*)alloc((size_t)M_ * D_ * 2);
    bf16*  gate     = (bf16*)alloc((size_t)M_ * I_ * 2);
    bf16*  hbc      = (bf16*)alloc((size_t)M_ * CONV_DIM * 2); // conv in; reused as yscan
    float* dtraw    = (float*)alloc((size_t)M_ * H_ * 4);
    bf16*  xs       = (bf16*)alloc((size_t)M_ * I_ * 2);
    float* bcbuf    = (float*)alloc((size_t)M_ * 128 * 4);     // B | C
    float* wcob     = (float*)alloc((size_t)M_ * H_ * 4);
    float* gmab     = (float*)alloc((size_t)M_ * H_ * 4);
    bf16*  sfin     = (bf16*)alloc((size_t)B_ * H_ * NC * 128 * 64 * 2); // 33.5 MiB
    (void)in_sizes; (void)n_in; (void)out_size;

    size_t needed = (size_t)(p - (char*)d_ws);
    if (needed > ws_size) return;   // diagnostic: absmax reads max|ref| (zeros)

    auto ing = [&](const float* src, bf16* dst, int n) {
        ingest_k<<<(n + 255) / 256, 256, 0, stream>>>(src, dst, n);
    };
    ing(x_in, xb, M_ * INP);
    ing(in_b, v_inb, D_);
    ing(norm_w, v_normw, L_ * D_);
    ing(conv_w, v_convw, L_ * 3 * CONV_DIM);
    ing(conv_b, v_convb, L_ * CONV_DIM);
    ing(gnorm_w, v_gnw, L_ * I_);
    ing(out_b, v_outb, OUT_);
    ing(code_b, v_codeb, CB_);

    dim3 tb(32, 8);
    transpose_any<<<dim3(32, 16), tb, 0, stream>>>(in_w, 0, wt_in, 512, 1024);
    transpose_any<<<dim3(16, 32), tb, 0, stream>>>(out_w, 0, wt_out, 1024, 512);
    transpose_any<<<dim3(32, 32), tb, 0, stream>>>(code_w, 0, wt_code, 1024, 1024);

    // h = x @ in_w + in_b
    gemm_bt<0><<<dim3(8, 64), 256, 0, stream>>>(xb, wt_in, INP, D_, v_inb,
                                                hbuf, nullptr, nullptr, nullptr);

    for (int i = 0; i < L_; ++i) {
        transpose_any<<<dim3(136, 32), tb, 0, stream>>>(mix_in_w, (size_t)i * 1024 * PROJ,
                                                        wt_big, 1024, PROJ);
        transpose_any<<<dim3(32, 64), tb, 0, stream>>>(mix_out_w, (size_t)i * 2048 * 1024,
                                                       wt_small, 2048, 1024);
        rmsnorm_k<<<M_, 256, 0, stream>>>(hbuf, v_normw + i * D_, hn);
        gemm_bt<1><<<dim3(34, 64), 256, 0, stream>>>(hn, wt_big, D_, PROJ, nullptr,
                                                     nullptr, gate, hbc, dtraw);
        conv_k<<<dim3(3, M_), 256, 0, stream>>>(hbc, v_convw + i * 3 * CONV_DIM,
                                                v_convb + i * CONV_DIM, xs, bcbuf);
        dtprep_k<<<(B_ * NC * H_ + 255) / 256, 256, 0, stream>>>(
            dtraw, dt_bias + i * H_, A_log + i * H_, wcob, gmab);
        scan_local_k<<<B_ * H_ * NC, 128, 0, stream>>>(xs, bcbuf, wcob, gmab,
                                                       Dvec + i * H_, hbc, sfin);
        scan_combine_k<<<B_ * H_, 128, 0, stream>>>(sfin, gmab);
        scan_correct_k<<<B_ * H_ * NC, 128, 0, stream>>>(sfin, gmab, bcbuf, hbc);
        gatednorm_k<<<M_, 256, 0, stream>>>(hbc, gate, v_gnw + i * I_, xs);
        gemm_bt<2><<<dim3(8, 64), 256, 0, stream>>>(xs, wt_small, I_, D_, nullptr,
                                                    hbuf, nullptr, nullptr, nullptr);
    }

    // heads -> fp32 d_out
    cast_f2b_k<<<(M_ * D_) / 1024, 256, 0, stream>>>(hbuf, hn);
    gemm_bt<0><<<dim3(4, 64), 256, 0, stream>>>(hn, wt_out, D_, OUT_, v_outb,
                                                outF0, nullptr, nullptr, nullptr);
    gemm_bt<0><<<dim3(8, 64), 256, 0, stream>>>(hn, wt_code, D_, CB_, v_codeb,
                                                outF1, nullptr, nullptr, nullptr);
}

// Round 6
// 2214.837 us; speedup vs baseline: 1.4137x; 1.4137x over previous
//
#include <hip/hip_runtime.h>
#include <hip/hip_bf16.h>

typedef __hip_bfloat16 bf16;
typedef __bf16 bfv8 __attribute__((ext_vector_type(8)));
typedef float fv4 __attribute__((ext_vector_type(4)));

#define B_  8
#define T_  1024
#define INP 512
#define D_  1024
#define I_  2048
#define N_  64
#define H_  16
#define P_  128
#define L_  4
#define OUT_ 512
#define CB_ 1024
#define CONV_DIM 2176
#define PROJ 4240
#define M_  (B_*T_)       // 8192 rows
#define TC  64            // scan chunk length
#define NC  (T_/TC)       // 16 chunks

typedef const __attribute__((address_space(1))) void gv_t;
typedef __attribute__((address_space(3))) void lv_t;

__device__ __forceinline__ void load_lds16(const bf16* g, bf16* l) {
    __builtin_amdgcn_global_load_lds((gv_t*)g, (lv_t*)l, 16, 0, 0);
}

// ---------------------------------------------------------------------------
// fp32 -> bf16 copy
// ---------------------------------------------------------------------------
__global__ __launch_bounds__(256) void ingest_k(const float* __restrict__ src,
                                                bf16* __restrict__ dst, int n) {
    int i = blockIdx.x * 256 + threadIdx.x;
    if (i >= n) return;
    dst[i] = __float2bfloat16(src[i]);
}

// ---------------------------------------------------------------------------
// Transpose fp32 [R][C] -> bf16 [Cp][R], zero-padding rows C..Cp.
// ---------------------------------------------------------------------------
__global__ __launch_bounds__(256) void transpose_any(const float* __restrict__ in,
                                                     size_t off,
                                                     bf16* __restrict__ out,
                                                     int R, int C) {
    __shared__ bf16 tile[32][33];
    int c0 = blockIdx.x * 32, r0 = blockIdx.y * 32;
    int tx = threadIdx.x, ty = threadIdx.y;
#pragma unroll
    for (int i = 0; i < 4; ++i) {
        int r = r0 + ty + i * 8, c = c0 + tx;
        bf16 v = __float2bfloat16(0.f);
        if (c < C) v = __float2bfloat16(in[off + (size_t)r * C + c]);
        tile[ty + i * 8][tx] = v;
    }
    __syncthreads();
#pragma unroll
    for (int i = 0; i < 4; ++i) {
        int c = c0 + ty + i * 8;
        out[(size_t)c * R + r0 + tx] = tile[tx][ty + i * 8];
    }
}

// ---------------------------------------------------------------------------
// GEMM: C[M,N] = A[M,K] @ Bt[N,K]^T. 128x128 tile, BK=32, 4 waves, 4x4 mfma.
// Staging via global_load_lds width=16 (m97 pattern).
// MODE 0: outF = acc + bias (fp32)    MODE 1: split gate/hBC/dt
// MODE 2: outF += acc (fp32)
// ---------------------------------------------------------------------------
template <int MODE>
__global__ __launch_bounds__(256) void gemm_bt(const bf16* __restrict__ A,
                                               const bf16* __restrict__ Bt,
                                               int K, int N,
                                               const bf16* __restrict__ bias,
                                               float* __restrict__ outF,
                                               bf16* __restrict__ outB,
                                               bf16* __restrict__ outB2,
                                               float* __restrict__ outF2) {
    __shared__ bf16 As[128 * 32];
    __shared__ bf16 Bs[128 * 32];
    const int tid = threadIdx.x;
    const int m0 = blockIdx.y * 128;
    const int n0 = blockIdx.x * 128;
    const int lane = tid & 63, wv = tid >> 6;
    const int wm = (wv >> 1) * 64, wn = (wv & 1) * 64;
    const int l16 = lane & 15, quad = lane >> 4;
    const int sr = lane >> 2, sc = (lane & 3) * 8;

    fv4 acc[4][4] = {};

    for (int k0 = 0; k0 < K; k0 += 32) {
        __syncthreads();
        {
            const bf16* gA0 = &A [(size_t)(m0 + wv * 16      + sr) * K + k0 + sc];
            const bf16* gA1 = &A [(size_t)(m0 + wv * 16 + 64 + sr) * K + k0 + sc];
            const bf16* gB0 = &Bt[(size_t)(n0 + wv * 16      + sr) * K + k0 + sc];
            const bf16* gB1 = &Bt[(size_t)(n0 + wv * 16 + 64 + sr) * K + k0 + sc];
            load_lds16(gA0, &As[(wv * 16) * 32]);
            load_lds16(gA1, &As[(wv * 16 + 64) * 32]);
            load_lds16(gB0, &Bs[(wv * 16) * 32]);
            load_lds16(gB1, &Bs[(wv * 16 + 64) * 32]);
        }
        __syncthreads();
        bfv8 afr[4], bfr[4];
#pragma unroll
        for (int i = 0; i < 4; ++i)
            afr[i] = *(const bfv8*)&As[(wm + i * 16 + l16) * 32 + quad * 8];
#pragma unroll
        for (int i = 0; i < 4; ++i)
            bfr[i] = *(const bfv8*)&Bs[(wn + i * 16 + l16) * 32 + quad * 8];
#pragma unroll
        for (int mt = 0; mt < 4; ++mt)
#pragma unroll
            for (int nt = 0; nt < 4; ++nt)
                acc[mt][nt] = __builtin_amdgcn_mfma_f32_16x16x32_bf16(
                    afr[mt], bfr[nt], acc[mt][nt], 0, 0, 0);
    }

#pragma unroll
    for (int mt = 0; mt < 4; ++mt) {
#pragma unroll
        for (int nt = 0; nt < 4; ++nt) {
#pragma unroll
            for (int i = 0; i < 4; ++i) {
                int row = m0 + wm + mt * 16 + quad * 4 + i;
                int col = n0 + wn + nt * 16 + l16;
                float v = acc[mt][nt][i];
                if (MODE == 0) {
                    v += __bfloat162float(bias[col]);
                    outF[(size_t)row * N + col] = v;
                } else if (MODE == 1) {
                    if (col < I_)
                        outB[(size_t)row * I_ + col] = __float2bfloat16(v);
                    else if (col < I_ + CONV_DIM)
                        outB2[(size_t)row * CONV_DIM + (col - I_)] = __float2bfloat16(v);
                    else if (col < PROJ)
                        outF2[(size_t)row * H_ + (col - (I_ + CONV_DIM))] = v;
                } else if (MODE == 2) {
                    outF[(size_t)row * N + col] += v;
                }
            }
        }
    }
}

// ---------------------------------------------------------------------------
__global__ __launch_bounds__(256) void rmsnorm_k(const float* __restrict__ x,
                                                 const bf16* __restrict__ w,
                                                 bf16* __restrict__ out) {
    int row = blockIdx.x, tid = threadIdx.x;
    float4 v = *(const float4*)&x[(size_t)row * D_ + tid * 4];
    float ss = v.x * v.x + v.y * v.y + v.z * v.z + v.w * v.w;
#pragma unroll
    for (int off = 32; off; off >>= 1) ss += __shfl_down(ss, off);
    __shared__ float sb[4];
    if ((tid & 63) == 0) sb[tid >> 6] = ss;
    __syncthreads();
    ss = sb[0] + sb[1] + sb[2] + sb[3];
    float rs = rsqrtf(ss * (1.f / D_) + 1e-6f);
    float xv[4] = {v.x, v.y, v.z, v.w};
#pragma unroll
    for (int j = 0; j < 4; ++j)
        out[(size_t)row * D_ + tid * 4 + j] =
            __float2bfloat16(xv[j] * rs * __bfloat162float(w[tid * 4 + j]));
}

// ---------------------------------------------------------------------------
__global__ __launch_bounds__(256) void gatednorm_k(const bf16* __restrict__ y,
                                                   const bf16* __restrict__ g,
                                                   const bf16* __restrict__ w,
                                                   bf16* __restrict__ out) {
    int row = blockIdx.x, tid = threadIdx.x;
    size_t base = (size_t)row * I_ + tid * 8;
    bf16 yv[8], gv[8];
    *(uint4*)yv = *(const uint4*)&y[base];
    *(uint4*)gv = *(const uint4*)&g[base];
    float vv[8]; float ss = 0.f;
#pragma unroll
    for (int j = 0; j < 8; ++j) {
        float yf = __bfloat162float(yv[j]);
        float gf = __bfloat162float(gv[j]);
        float sig = 1.f / (1.f + expf(-gf));
        vv[j] = yf * gf * sig;
        ss += vv[j] * vv[j];
    }
#pragma unroll
    for (int off = 32; off; off >>= 1) ss += __shfl_down(ss, off);
    __shared__ float sb[4];
    if ((tid & 63) == 0) sb[tid >> 6] = ss;
    __syncthreads();
    ss = sb[0] + sb[1] + sb[2] + sb[3];
    float rs = rsqrtf(ss * (1.f / I_) + 1e-6f);
    bf16 ov[8];
#pragma unroll
    for (int j = 0; j < 8; ++j)
        ov[j] = __float2bfloat16(vv[j] * rs * __bfloat162float(w[tid * 8 + j]));
    *(uint4*)&out[base] = *(uint4*)ov;
}

// ---------------------------------------------------------------------------
__global__ __launch_bounds__(256) void conv_k(const bf16* __restrict__ hbc,
                                              const bf16* __restrict__ w,
                                              const bf16* __restrict__ bias,
                                              bf16* __restrict__ xs,
                                              float* __restrict__ bc) {
    int cq = blockIdx.x * 256 + threadIdx.x;
    if (cq >= CONV_DIM / 4) return;
    int c = cq * 4;
    int bt = blockIdx.y;
    int t = bt & (T_ - 1);
    float acc[4];
#pragma unroll
    for (int j = 0; j < 4; ++j) acc[j] = __bfloat162float(bias[c + j]);
#pragma unroll
    for (int k = 0; k < 3; ++k) {
        int tt = t - 2 + k;
        if (tt < 0) continue;
        const bf16* src = &hbc[(size_t)(bt - 2 + k) * CONV_DIM + c];
#pragma unroll
        for (int j = 0; j < 4; ++j)
            acc[j] = fmaf(__bfloat162float(w[k * CONV_DIM + c + j]),
                          __bfloat162float(src[j]), acc[j]);
    }
#pragma unroll
    for (int j = 0; j < 4; ++j) {
        float v = acc[j];
        v = v / (1.f + expf(-v));     // silu
        if (c + j < I_) xs[(size_t)bt * I_ + c + j] = __float2bfloat16(v);
        else            bc[(size_t)bt * 128 + (c + j - I_)] = v;
    }
}

// ---------------------------------------------------------------------------
// dt prep: per (b,h,chunk): dt = softplus(dtraw+bias); gamma = cumprod(exp(dt*a));
// wco = dt/gamma; gma = gamma.
// ---------------------------------------------------------------------------
__global__ __launch_bounds__(256) void dtprep_k(const float* __restrict__ dtraw,
                                                const float* __restrict__ dtb,
                                                const float* __restrict__ alog,
                                                float* __restrict__ wco,
                                                float* __restrict__ gma) {
    int idx = blockIdx.x * 256 + threadIdx.x;       // b*256 + ci*16 + h
    if (idx >= B_ * NC * H_) return;
    int h = idx & 15, ci = (idx >> 4) & (NC - 1), b = idx >> 8;
    float a = -expf(alog[h]);
    float bz = dtb[h];
    float g = 1.f;
    int base = (b * T_ + ci * TC) * H_ + h;
    for (int s = 0; s < TC; ++s) {
        float z = dtraw[base + s * H_] + bz;
        float dt = fmaxf(z, 0.f) + log1pf(expf(-fabsf(z)));
        g *= expf(dt * a);
        wco[base + s * H_] = dt / g;
        gma[base + s * H_] = g;
    }
}

// ---------------------------------------------------------------------------
// Scan pass A (normalized form): per (b,h,chunk) local scan from zero state.
// ---------------------------------------------------------------------------
__global__ __launch_bounds__(128) void scan_local_k(const bf16* __restrict__ xs,
                                                    const float* __restrict__ bc,
                                                    const float* __restrict__ wco,
                                                    const float* __restrict__ gma,
                                                    const float* __restrict__ dvec,
                                                    bf16* __restrict__ yout,
                                                    bf16* __restrict__ sfin) {
    int bid = blockIdx.x;                   // b*256 + h*16 + ci
    int ci = bid & (NC - 1);
    int h  = (bid >> 4) & (H_ - 1);
    int b  = bid >> 8;
    int p = threadIdx.x;
    float Dv = dvec[h];
    float st[64];
#pragma unroll
    for (int n = 0; n < 64; ++n) st[n] = 0.f;
    int bt0 = b * T_ + ci * TC;
    const bf16* xptr = xs + (size_t)bt0 * I_ + h * P_ + p;
    bf16* yptr = yout + (size_t)bt0 * I_ + h * P_ + p;
    float xv_n = __bfloat162float(xptr[0]);
    for (int s = 0; s < TC; ++s) {
        float xv = xv_n;
        if (s + 1 < TC) xv_n = __bfloat162float(xptr[(size_t)(s + 1) * I_]);
        float w = wco[(bt0 + s) * H_ + h];          // uniform
        float g = gma[(bt0 + s) * H_ + h];
        float cc = w * xv;
        const float4* B4 = (const float4*)&bc[(size_t)(bt0 + s) * 128];
#pragma unroll
        for (int j = 0; j < 16; ++j) {
            float4 bv = B4[j];
            st[4 * j + 0] = fmaf(cc, bv.x, st[4 * j + 0]);
            st[4 * j + 1] = fmaf(cc, bv.y, st[4 * j + 1]);
            st[4 * j + 2] = fmaf(cc, bv.z, st[4 * j + 2]);
            st[4 * j + 3] = fmaf(cc, bv.w, st[4 * j + 3]);
        }
        float y0 = 0.f, y1 = 0.f, y2 = 0.f, y3 = 0.f;
#pragma unroll
        for (int j = 0; j < 16; ++j) {
            float4 cv = B4[16 + j];
            y0 = fmaf(st[4 * j + 0], cv.x, y0);
            y1 = fmaf(st[4 * j + 1], cv.y, y1);
            y2 = fmaf(st[4 * j + 2], cv.z, y2);
            y3 = fmaf(st[4 * j + 3], cv.w, y3);
        }
        yptr[(size_t)s * I_] = __float2bfloat16(fmaf(g, (y0 + y1) + (y2 + y3), Dv * xv));
    }
    float G = gma[(bt0 + TC - 1) * H_ + h];
    bf16* sf = sfin + (size_t)bid * (128 * 64);
#pragma unroll
    for (int n = 0; n < 64; ++n) sf[n * 128 + p] = __float2bfloat16(st[n] * G);
}

// ---------------------------------------------------------------------------
// Pass B: chunk combine, PARALLEL over (b,h,n,p) — sequential only in ci.
// grid = B_*H_*64 blocks (8192), block = 128 (p). In-place: sbuf[ci] becomes
// S_init of chunk ci; S carries the running end-of-chunk state.
// ---------------------------------------------------------------------------
__global__ __launch_bounds__(128) void scan_combine_k(bf16* __restrict__ sbuf,
                                                      const float* __restrict__ gma) {
    int bid = blockIdx.x;                   // b*H*64 + h*64 + n
    int n = bid & 63;
    int h = (bid >> 6) & (H_ - 1);
    int b = bid >> 10;
    int p = threadIdx.x;
    size_t base0 = ((size_t)(b * (H_ * NC) + h * NC) * (128 * 64)) + n * 128 + p;
    int gbase = b * T_ * H_ + h;
    float S = 0.f;
#pragma unroll
    for (int ci = 0; ci < NC; ++ci) {
        bf16* addr = sbuf + base0 + (size_t)ci * (128 * 64);
        float tmp = __bfloat162float(*addr);            // S_fin of chunk ci
        *addr = __float2bfloat16(S);                    // S_init of chunk ci
        float G = gma[gbase + (ci * TC + TC - 1) * H_]; // uniform per block
        S = fmaf(G, S, tmp);
    }
}

// ---------------------------------------------------------------------------
// Pass C: y += gamma_t * (C_t . S_init)
// ---------------------------------------------------------------------------
__global__ __launch_bounds__(128) void scan_correct_k(const bf16* __restrict__ sinit,
                                                      const float* __restrict__ gma,
                                                      const float* __restrict__ bc,
                                                      bf16* __restrict__ yout) {
    int bid = blockIdx.x;
    int ci = bid & (NC - 1);
    if (ci == 0) return;
    int h = (bid >> 4) & (H_ - 1);
    int b = bid >> 8;
    int p = threadIdx.x;
    const bf16* sb = sinit + (size_t)bid * (128 * 64);
    float S[64];
#pragma unroll
    for (int n = 0; n < 64; ++n) S[n] = __bfloat162float(sb[n * 128 + p]);
    int bt0 = b * T_ + ci * TC;
    bf16* yptr = yout + (size_t)bt0 * I_ + h * P_ + p;
    for (int s = 0; s < TC; ++s) {
        float g = gma[(bt0 + s) * H_ + h];
        const float4* C4 = (const float4*)&bc[(size_t)(bt0 + s) * 128 + 64];
        float y0 = 0.f, y1 = 0.f, y2 = 0.f, y3 = 0.f;
#pragma unroll
        for (int j = 0; j < 16; ++j) {
            float4 cv = C4[j];
            y0 = fmaf(S[4 * j + 0], cv.x, y0);
            y1 = fmaf(S[4 * j + 1], cv.y, y1);
            y2 = fmaf(S[4 * j + 2], cv.z, y2);
            y3 = fmaf(S[4 * j + 3], cv.w, y3);
        }
        float y = __bfloat162float(yptr[(size_t)s * I_]);
        yptr[(size_t)s * I_] = __float2bfloat16(fmaf(g, (y0 + y1) + (y2 + y3), y));
    }
}

// ---------------------------------------------------------------------------
__global__ __launch_bounds__(256) void cast_f2b_k(const float* __restrict__ in,
                                                  bf16* __restrict__ out) {
    int i = (blockIdx.x * 256 + threadIdx.x) * 4;
    float4 v = *(const float4*)&in[i];
    bf16 ov[4] = {__float2bfloat16(v.x), __float2bfloat16(v.y),
                  __float2bfloat16(v.z), __float2bfloat16(v.w)};
    *(uint2*)&out[i] = *(uint2*)ov;
}

// ---------------------------------------------------------------------------

static inline size_t align256(size_t x) { return (x + 255) & ~(size_t)255; }

extern "C" void kernel_launch(void* const* d_in, const int* in_sizes, int n_in,
                              void* d_out, int out_size, void* d_ws, size_t ws_size,
                              hipStream_t stream) {
    const float* x_in     = (const float*)d_in[0];
    const float* in_w     = (const float*)d_in[1];
    const float* in_b     = (const float*)d_in[2];
    const float* norm_w   = (const float*)d_in[3];
    const float* mix_in_w = (const float*)d_in[4];
    const float* conv_w   = (const float*)d_in[5];
    const float* conv_b   = (const float*)d_in[6];
    const float* dt_bias  = (const float*)d_in[7];
    const float* A_log    = (const float*)d_in[8];
    const float* Dvec     = (const float*)d_in[9];
    const float* gnorm_w  = (const float*)d_in[10];
    const float* mix_out_w= (const float*)d_in[11];
    const float* out_w    = (const float*)d_in[12];
    const float* out_b    = (const float*)d_in[13];
    const float* code_w   = (const float*)d_in[14];
    const float* code_b   = (const float*)d_in[15];
    float* outF0 = (float*)d_out;                       // [8192][512]
    float* outF1 = (float*)d_out + (size_t)M_ * OUT_;   // [8192][1024]

    char* p = (char*)d_ws;
    auto alloc = [&](size_t bytes) -> char* { char* r = p; p += align256(bytes); return r; };

    bf16*  xb       = (bf16*)alloc((size_t)M_ * INP * 2);
    bf16*  v_inb    = (bf16*)alloc(D_ * 2);
    bf16*  v_normw  = (bf16*)alloc(L_ * D_ * 2);
    bf16*  v_convw  = (bf16*)alloc(L_ * 3 * CONV_DIM * 2);
    bf16*  v_convb  = (bf16*)alloc(L_ * CONV_DIM * 2);
    bf16*  v_gnw    = (bf16*)alloc(L_ * I_ * 2);
    bf16*  v_outb   = (bf16*)alloc(OUT_ * 2);
    bf16*  v_codeb  = (bf16*)alloc(CB_ * 2);
    bf16*  wt_in    = (bf16*)alloc((size_t)1024 * 512 * 2);
    bf16*  wt_big   = (bf16*)alloc((size_t)4352 * 1024 * 2);   // per-layer reuse
    bf16*  wt_small = (bf16*)alloc((size_t)1024 * 2048 * 2);   // per-layer reuse
    bf16*  wt_out   = (bf16*)alloc((size_t)512 * 1024 * 2);
    bf16*  wt_code  = (bf16*)alloc((size_t)1024 * 1024 * 2);
    float* hbuf     = (float*)alloc((size_t)M_ * D_ * 4);      // residual fp32
    bf16*  hn       = (bf16*)alloc((size_t)M_ * D_ * 2);
    bf16*  gate     = (bf16*)alloc((size_t)M_ * I_ * 2);
    bf16*  hbc      = (bf16*)alloc((size_t)M_ * CONV_DIM * 2); // conv in; reused as yscan
    float* dtraw    = (float*)alloc((size_t)M_ * H_ * 4);
    bf16*  xs       = (bf16*)alloc((size_t)M_ * I_ * 2);
    float* bcbuf    = (float*)alloc((size_t)M_ * 128 * 4);     // B | C
    float* wcob     = (float*)alloc((size_t)M_ * H_ * 4);
    float* gmab     = (float*)alloc((size_t)M_ * H_ * 4);
    bf16*  sfin     = (bf16*)alloc((size_t)B_ * H_ * NC * 128 * 64 * 2); // 33.5 MiB
    (void)in_sizes; (void)n_in; (void)out_size;

    size_t needed = (size_t)(p - (char*)d_ws);
    if (needed > ws_size) return;   // diagnostic: absmax reads max|ref| (zeros)

    auto ing = [&](const float* src, bf16* dst, int n) {
        ingest_k<<<(n + 255) / 256, 256, 0, stream>>>(src, dst, n);
    };
    ing(x_in, xb, M_ * INP);
    ing(in_b, v_inb, D_);
    ing(norm_w, v_normw, L_ * D_);
    ing(conv_w, v_convw, L_ * 3 * CONV_DIM);
    ing(conv_b, v_convb, L_ * CONV_DIM);
    ing(gnorm_w, v_gnw, L_ * I_);
    ing(out_b, v_outb, OUT_);
    ing(code_b, v_codeb, CB_);

    dim3 tb(32, 8);
    transpose_any<<<dim3(32, 16), tb, 0, stream>>>(in_w, 0, wt_in, 512, 1024);
    transpose_any<<<dim3(16, 32), tb, 0, stream>>>(out_w, 0, wt_out, 1024, 512);
    transpose_any<<<dim3(32, 32), tb, 0, stream>>>(code_w, 0, wt_code, 1024, 1024);

    // h = x @ in_w + in_b
    gemm_bt<0><<<dim3(8, 64), 256, 0, stream>>>(xb, wt_in, INP, D_, v_inb,
                                                hbuf, nullptr, nullptr, nullptr);

    for (int i = 0; i < L_; ++i) {
        transpose_any<<<dim3(136, 32), tb, 0, stream>>>(mix_in_w, (size_t)i * 1024 * PROJ,
                                                        wt_big, 1024, PROJ);
        transpose_any<<<dim3(32, 64), tb, 0, stream>>>(mix_out_w, (size_t)i * 2048 * 1024,
                                                       wt_small, 2048, 1024);
        rmsnorm_k<<<M_, 256, 0, stream>>>(hbuf, v_normw + i * D_, hn);
        gemm_bt<1><<<dim3(34, 64), 256, 0, stream>>>(hn, wt_big, D_, PROJ, nullptr,
                                                     nullptr, gate, hbc, dtraw);
        conv_k<<<dim3(3, M_), 256, 0, stream>>>(hbc, v_convw + i * 3 * CONV_DIM,
                                                v_convb + i * CONV_DIM, xs, bcbuf);
        dtprep_k<<<(B_ * NC * H_ + 255) / 256, 256, 0, stream>>>(
            dtraw, dt_bias + i * H_, A_log + i * H_, wcob, gmab);
        scan_local_k<<<B_ * H_ * NC, 128, 0, stream>>>(xs, bcbuf, wcob, gmab,
                                                       Dvec + i * H_, hbc, sfin);
        scan_combine_k<<<B_ * H_ * 64, 128, 0, stream>>>(sfin, gmab);
        scan_correct_k<<<B_ * H_ * NC, 128, 0, stream>>>(sfin, gmab, bcbuf, hbc);
        gatednorm_k<<<M_, 256, 0, stream>>>(hbc, gate, v_gnw + i * I_, xs);
        gemm_bt<2><<<dim3(8, 64), 256, 0, stream>>>(xs, wt_small, I_, D_, nullptr,
                                                    hbuf, nullptr, nullptr, nullptr);
    }

    // heads -> fp32 d_out
    cast_f2b_k<<<(M_ * D_) / 1024, 256, 0, stream>>>(hbuf, hn);
    gemm_bt<0><<<dim3(4, 64), 256, 0, stream>>>(hn, wt_out, D_, OUT_, v_outb,
                                                outF0, nullptr, nullptr, nullptr);
    gemm_bt<0><<<dim3(8, 64), 256, 0, stream>>>(hn, wt_code, D_, CB_, v_codeb,
                                                outF1, nullptr, nullptr, nullptr);
}